// Round 10
// baseline (58.444 us; speedup 1.0000x reference)
//
#include <hip/hip_runtime.h>
#include <stdint.h>

namespace {

constexpr int kB = 8;
constexpr int kV = 5023;
constexpr int kF = 9976;
constexpr int kH = 512;
constexpr int kW = 512;
constexpr int kL = 5;
constexpr int kHW = kH * kW;
constexpr int kQ = kHW / 4;   // pixel quads per batch
constexpr int kCap = 32;      // max faces per vertex (lambda ~ 6)

typedef float nfloat4 __attribute__((ext_vector_type(4)));
typedef int nint4 __attribute__((ext_vector_type(4)));

__device__ __forceinline__ float h2f(uint32_t u) {
  _Float16 h;
  uint16_t s = (uint16_t)u;
  __builtin_memcpy(&h, &s, 2);
  return (float)h;
}
__device__ __forceinline__ uint32_t f2h(float f) {
  _Float16 h = (_Float16)f;
  uint16_t s;
  __builtin_memcpy(&s, &h, 2);
  return (uint32_t)s;
}

__device__ __forceinline__ void cross3(float ax, float ay, float az,
                                       float bx, float by, float bz,
                                       float& cx, float& cy, float& cz) {
  cx = ay * bz - az * by;
  cy = az * bx - ax * bz;
  cz = ax * by - ay * bx;
}

__device__ __forceinline__ nfloat4 nt_loadf4(const float4* p) {
  return __builtin_nontemporal_load((const nfloat4*)p);
}
__device__ __forceinline__ nint4 nt_loadi4(const int4* p) {
  return __builtin_nontemporal_load((const nint4*)p);
}

// Zero adjacency counters + pre-normalize lights into packed float4 pairs.
__global__ void init_kernel(int* __restrict__ cnt,
                            const float* __restrict__ lights,
                            float4* __restrict__ ldir4) {
  int idx = blockIdx.x * blockDim.x + threadIdx.x;
  for (int i = idx; i < kV; i += gridDim.x * blockDim.x) cnt[i] = 0;
  if (idx < kB * kL) {
    float dx = lights[idx * 6 + 0];
    float dy = lights[idx * 6 + 1];
    float dz = lights[idx * 6 + 2];
    float inv = 1.0f / fmaxf(sqrtf(dx * dx + dy * dy + dz * dz), 1e-12f);
    ldir4[idx * 2 + 0] = make_float4(dx * inv, dy * inv, dz * inv, 0.0f);
    ldir4[idx * 2 + 1] =
        make_float4(lights[idx * 6 + 3], lights[idx * 6 + 4], lights[idx * 6 + 5], 0.0f);
  }
}

// Fused: threads [0,kF) build vertex->face adjacency (int atomics);
// threads [kF, kF+kB*kF) compute per-(b,f) face normals for both meshes.
__global__ void prep_kernel(const float* __restrict__ verts,
                            const float* __restrict__ tverts,
                            const int* __restrict__ faces,
                            int* __restrict__ cnt,
                            int* __restrict__ adj,
                            float4* __restrict__ fn) {
  int idx = blockIdx.x * blockDim.x + threadIdx.x;
  if (idx < kF) {
    int f = idx;
#pragma unroll
    for (int c = 0; c < 3; ++c) {
      int v = faces[f * 3 + c];
      int slot = atomicAdd(&cnt[v], 1);
      if (slot < kCap) adj[v * kCap + slot] = f;
    }
    return;
  }
  idx -= kF;
  if (idx >= kB * kF) return;
  int b = idx / kF;
  int f = idx - b * kF;
  int i0 = faces[f * 3 + 0];
  int i1 = faces[f * 3 + 1];
  int i2 = faces[f * 3 + 2];

  float nx, ny, nz, tx, ty, tz;
  {
    const float* vb = verts + (size_t)b * kV * 3;
    float v0x = vb[i0 * 3 + 0], v0y = vb[i0 * 3 + 1], v0z = vb[i0 * 3 + 2];
    float v1x = vb[i1 * 3 + 0], v1y = vb[i1 * 3 + 1], v1z = vb[i1 * 3 + 2];
    float v2x = vb[i2 * 3 + 0], v2y = vb[i2 * 3 + 1], v2z = vb[i2 * 3 + 2];
    cross3(v1x - v0x, v1y - v0y, v1z - v0z, v2x - v0x, v2y - v0y, v2z - v0z,
           nx, ny, nz);
  }
  {
    const float* vb = tverts + (size_t)b * kV * 3;
    // fp-faithful to reference: add 10 to z BEFORE differencing
    float v0x = vb[i0 * 3 + 0], v0y = vb[i0 * 3 + 1], v0z = vb[i0 * 3 + 2] + 10.0f;
    float v1x = vb[i1 * 3 + 0], v1y = vb[i1 * 3 + 1], v1z = vb[i1 * 3 + 2] + 10.0f;
    float v2x = vb[i2 * 3 + 0], v2y = vb[i2 * 3 + 1], v2z = vb[i2 * 3 + 2] + 10.0f;
    cross3(v1x - v0x, v1y - v0y, v1z - v0z, v2x - v0x, v2y - v0y, v2z - v0z,
           tx, ty, tz);
  }
  fn[(size_t)idx * 2 + 0] = make_float4(nx, ny, nz, tx);
  fn[(size_t)idx * 2 + 1] = make_float4(ty, tz, 0.0f, 0.0f);
}

// Per (b,v): gather-sum adjacent face normals, normalize, write packed
// 16B vertex record {n fp16 x3, tz fp32}.
__global__ void gather_normalize_kernel(const int* __restrict__ cnt,
                                        const int* __restrict__ adj,
                                        const float4* __restrict__ fn,
                                        uint4* __restrict__ vrec) {
  int idx = blockIdx.x * blockDim.x + threadIdx.x;
  if (idx >= kB * kV) return;
  int b = idx / kV;
  int v = idx - b * kV;
  int e = min(cnt[v], kCap);
  float nx = 0.f, ny = 0.f, nz = 0.f, tx = 0.f, ty = 0.f, tzv = 0.f;
  const int* av = adj + v * kCap;
  for (int j = 0; j < e; ++j) {
    int f = av[j];
    size_t k = ((size_t)b * kF + f) * 2;
    float4 a = fn[k];
    float4 c = fn[k + 1];
    nx += a.x;
    ny += a.y;
    nz += a.z;
    tx += a.w;
    ty += c.x;
    tzv += c.y;
  }
  float inv = 1.0f / fmaxf(sqrtf(nx * nx + ny * ny + nz * nz), 1e-6f);
  float invt = 1.0f / fmaxf(sqrtf(tx * tx + ty * ty + tzv * tzv), 1e-6f);
  uint4 r;
  r.x = f2h(nx * inv) | (f2h(ny * inv) << 16);
  r.y = f2h(nz * inv);
  r.z = __float_as_uint(tzv * invt);
  r.w = 0;
  vrec[idx] = r;
}

// Per (b,f): pull 3 packed vertex records (3 x 16B vector gathers) and
// repack into the 32B face record (same layout pixel4 expects).
__global__ void faceattr_kernel(const int* __restrict__ faces,
                                const uint4* __restrict__ vrec,
                                uint4* __restrict__ fattr) {
  int idx = blockIdx.x * blockDim.x + threadIdx.x;
  if (idx >= kB * kF) return;
  int b = idx / kF;
  int f = idx - b * kF;
  int i0 = faces[f * 3 + 0];
  int i1 = faces[f * 3 + 1];
  int i2 = faces[f * 3 + 2];
  const uint4* vb = vrec + (size_t)b * kV;
  uint4 r0 = vb[i0];
  uint4 r1 = vb[i1];
  uint4 r2 = vb[i2];
  uint4 w0, w1;
  w0.x = r0.x;                                      // n0x | n0y
  w0.y = (r0.y & 0xffffu) | (r1.x << 16);           // n0z | n1x
  w0.z = (r1.x >> 16) | ((r1.y & 0xffffu) << 16);   // n1y | n1z
  w0.w = r2.x;                                      // n2x | n2y
  w1.x = r2.y & 0xffffu;                            // n2z
  w1.y = r0.z;                                      // tz0 (f32 bits)
  w1.z = r1.z;                                      // tz1
  w1.w = r2.z;                                      // tz2
  fattr[(size_t)idx * 2 + 0] = w0;
  fattr[(size_t)idx * 2 + 1] = w1;
}

// 4 pixels per thread. Round-8 body + NT loads on all read-once streaming
// inputs (p2f/bary/img) so they don't evict the L2-resident fattr table.
__global__ void __launch_bounds__(256) pixel4_kernel(
    const int4* __restrict__ p2f4,
    const float4* __restrict__ bary4,
    const uint4* __restrict__ fattr,
    const float4* __restrict__ ldir4,
    const float4* __restrict__ img4,
    float4* __restrict__ out4) {
  int g = blockIdx.x * blockDim.x + threadIdx.x;
  if (g >= kB * kQ) return;
  int b = g / kQ;
  int q = g - b * kQ;

  nint4 f4 = nt_loadi4(&p2f4[g]);
  nfloat4 w0 = nt_loadf4(&bary4[(size_t)g * 3 + 0]);
  nfloat4 w1 = nt_loadf4(&bary4[(size_t)g * 3 + 1]);
  nfloat4 w2 = nt_loadf4(&bary4[(size_t)g * 3 + 2]);

  int fi[4] = {f4.x, f4.y, f4.z, f4.w};
  float bw[4][3] = {{w0.x, w0.y, w0.z},
                    {w0.w, w1.x, w1.y},
                    {w1.z, w1.w, w2.x},
                    {w2.y, w2.z, w2.w}};

  // Issue all 8 gathers (independent -> deep MLP).
  uint4 A[4], T[4];
  bool valid[4];
#pragma unroll
  for (int k = 0; k < 4; ++k) {
    bool v = fi[k] < kF;
    valid[k] = v;
    int f = v ? fi[k] : (kF - 1);
    size_t base = ((size_t)b * kF + f) * 2;
    A[k] = fattr[base + 0];
    T[k] = fattr[base + 1];
  }

  size_t ibase = (size_t)b * 3 * kQ + q;
  nfloat4 im0 = nt_loadf4(&img4[ibase + 0 * (size_t)kQ]);
  nfloat4 im1 = nt_loadf4(&img4[ibase + 1 * (size_t)kQ]);
  nfloat4 im2 = nt_loadf4(&img4[ibase + 2 * (size_t)kQ]);
  float im[3][4] = {{im0.x, im0.y, im0.z, im0.w},
                    {im1.x, im1.y, im1.z, im1.w},
                    {im2.x, im2.y, im2.z, im2.w}};

  // Light data: wave-uniform b -> scalar loads.
  int bu = __builtin_amdgcn_readfirstlane(b);
  const float4* lb4 = ldir4 + (size_t)bu * kL * 2;
  float ld[kL][3], lc[kL][3];
#pragma unroll
  for (int l = 0; l < kL; ++l) {
    float4 d = lb4[l * 2 + 0];
    float4 c = lb4[l * 2 + 1];
    ld[l][0] = d.x;
    ld[l][1] = d.y;
    ld[l][2] = d.z;
    lc[l][0] = c.x;
    lc[l][1] = c.y;
    lc[l][2] = c.z;
  }

  float o[3][4];
#pragma unroll
  for (int k = 0; k < 4; ++k) {
    float b0 = bw[k][0], b1 = bw[k][1], b2 = bw[k][2];
    float inv = 1.0f / (b0 + b1 + b2);
    b0 *= inv;
    b1 *= inv;
    b2 *= inv;
    float n0x = h2f(A[k].x), n0y = h2f(A[k].x >> 16);
    float n0z = h2f(A[k].y), n1x = h2f(A[k].y >> 16);
    float n1y = h2f(A[k].z), n1z = h2f(A[k].z >> 16);
    float n2x = h2f(A[k].w), n2y = h2f(A[k].w >> 16);
    float n2z = h2f(T[k].x);
    float tz0 = __uint_as_float(T[k].y);
    float tz1 = __uint_as_float(T[k].z);
    float tz2 = __uint_as_float(T[k].w);

    float tzi = b0 * tz0 + b1 * tz1 + b2 * tz2;
    bool alpha = valid[k] && (tzi < 0.15f);
    float nx = b0 * n0x + b1 * n1x + b2 * n2x;
    float ny = b0 * n0y + b1 * n1y + b2 * n2y;
    float nz = b0 * n0z + b1 * n1z + b2 * n2z;
    float s0 = 0.f, s1 = 0.f, s2 = 0.f;
#pragma unroll
    for (int l = 0; l < kL; ++l) {
      float d = nx * ld[l][0] + ny * ld[l][1] + nz * ld[l][2];
      d = fminf(fmaxf(d, 0.0f), 1.0f);
      s0 += d * lc[l][0];
      s1 += d * lc[l][1];
      s2 += d * lc[l][2];
    }
    const float kk = (180.0f / 255.0f) / (float)kL;
    o[0][k] = alpha ? kk * s0 : im[0][k];
    o[1][k] = alpha ? kk * s1 : im[1][k];
    o[2][k] = alpha ? kk * s2 : im[2][k];
  }

#pragma unroll
  for (int c = 0; c < 3; ++c) {
    nfloat4 v = {o[c][0], o[c][1], o[c][2], o[c][3]};
    __builtin_nontemporal_store(v, (nfloat4*)&out4[ibase + c * (size_t)kQ]);
  }
}

}  // namespace

extern "C" void kernel_launch(void* const* d_in, const int* in_sizes, int n_in,
                              void* d_out, int out_size, void* d_ws, size_t ws_size,
                              hipStream_t stream) {
  const float* vertices = (const float*)d_in[0];
  const float* tvertices = (const float*)d_in[1];
  const float* lights = (const float*)d_in[2];
  const float* images = (const float*)d_in[3];
  const float* bary = (const float*)d_in[4];
  const int* faces = (const int*)d_in[5];
  const int* p2f = (const int*)d_in[6];
  float* out = (float*)d_out;

  // workspace layout (16B-aligned chunks)
  char* ws = (char*)d_ws;
  int* cnt = (int*)ws;                                   // kV ints
  ws += ((size_t)kV * sizeof(int) + 15) & ~15ull;
  int* adj = (int*)ws;                                   // kV*kCap ints
  ws += ((size_t)kV * kCap * sizeof(int) + 15) & ~15ull;
  float4* fn = (float4*)ws;                              // kB*kF*2 float4
  ws += (size_t)kB * kF * 2 * sizeof(float4);
  uint4* vrec = (uint4*)ws;                              // kB*kV uint4
  ws += (size_t)kB * kV * sizeof(uint4);
  float4* ldir4 = (float4*)ws;                           // kB*kL*2 float4
  ws += (size_t)kB * kL * 2 * sizeof(float4);
  uint4* fattr = (uint4*)ws;                             // kB*kF*2 uint4

  {
    init_kernel<<<20, 256, 0, stream>>>(cnt, lights, ldir4);
  }
  {
    int n = kF + kB * kF;
    prep_kernel<<<(n + 255) / 256, 256, 0, stream>>>(vertices, tvertices, faces, cnt,
                                                     adj, fn);
  }
  {
    int n = kB * kV;
    gather_normalize_kernel<<<(n + 255) / 256, 256, 0, stream>>>(cnt, adj, fn, vrec);
  }
  {
    int n = kB * kF;
    faceattr_kernel<<<(n + 255) / 256, 256, 0, stream>>>(faces, vrec, fattr);
  }
  {
    int n = kB * kQ;
    pixel4_kernel<<<(n + 255) / 256, 256, 0, stream>>>((const int4*)p2f, (const float4*)bary,
                                                       fattr, ldir4, (const float4*)images,
                                                       (float4*)out);
  }
}

// Round 11
// 48.378 us; speedup vs baseline: 1.2081x; 1.2081x over previous
//
#include <hip/hip_runtime.h>
#include <stdint.h>

namespace {

constexpr int kB = 8;
constexpr int kV = 5023;
constexpr int kF = 9976;
constexpr int kH = 512;
constexpr int kW = 512;
constexpr int kL = 5;
constexpr int kHW = kH * kW;
constexpr int kQ = kHW / 4;   // pixel quads per batch (65536, pow2)
constexpr int kCap = 32;      // max faces per vertex (lambda ~ 6)

typedef float nfloat4 __attribute__((ext_vector_type(4)));

__device__ __forceinline__ float h2f(uint32_t u) {
  _Float16 h;
  uint16_t s = (uint16_t)u;
  __builtin_memcpy(&h, &s, 2);
  return (float)h;
}
__device__ __forceinline__ uint32_t f2h(float f) {
  _Float16 h = (_Float16)f;
  uint16_t s;
  __builtin_memcpy(&s, &h, 2);
  return (uint32_t)s;
}

__device__ __forceinline__ void cross3(float ax, float ay, float az,
                                       float bx, float by, float bz,
                                       float& cx, float& cy, float& cz) {
  cx = ay * bz - az * by;
  cy = az * bx - ax * bz;
  cz = ax * by - ay * bx;
}

// Zero adjacency counters + pre-normalize lights into packed float4 pairs.
__global__ void init_kernel(int* __restrict__ cnt,
                            const float* __restrict__ lights,
                            float4* __restrict__ ldir4) {
  int idx = blockIdx.x * blockDim.x + threadIdx.x;
  for (int i = idx; i < kV; i += gridDim.x * blockDim.x) cnt[i] = 0;
  if (idx < kB * kL) {
    float dx = lights[idx * 6 + 0];
    float dy = lights[idx * 6 + 1];
    float dz = lights[idx * 6 + 2];
    float inv = 1.0f / fmaxf(sqrtf(dx * dx + dy * dy + dz * dz), 1e-12f);
    ldir4[idx * 2 + 0] = make_float4(dx * inv, dy * inv, dz * inv, 0.0f);
    ldir4[idx * 2 + 1] =
        make_float4(lights[idx * 6 + 3], lights[idx * 6 + 4], lights[idx * 6 + 5], 0.0f);
  }
}

// Fused: threads [0,kF) build vertex->face adjacency (int atomics);
// threads [kF, kF+kB*kF) compute per-(b,f) face normals for both meshes.
__global__ void prep_kernel(const float* __restrict__ verts,
                            const float* __restrict__ tverts,
                            const int* __restrict__ faces,
                            int* __restrict__ cnt,
                            int* __restrict__ adj,
                            float4* __restrict__ fn) {
  int idx = blockIdx.x * blockDim.x + threadIdx.x;
  if (idx < kF) {
    int f = idx;
#pragma unroll
    for (int c = 0; c < 3; ++c) {
      int v = faces[f * 3 + c];
      int slot = atomicAdd(&cnt[v], 1);
      if (slot < kCap) adj[v * kCap + slot] = f;
    }
    return;
  }
  idx -= kF;
  if (idx >= kB * kF) return;
  int b = idx / kF;
  int f = idx - b * kF;
  int i0 = faces[f * 3 + 0];
  int i1 = faces[f * 3 + 1];
  int i2 = faces[f * 3 + 2];

  float nx, ny, nz, tx, ty, tz;
  {
    const float* vb = verts + (size_t)b * kV * 3;
    float v0x = vb[i0 * 3 + 0], v0y = vb[i0 * 3 + 1], v0z = vb[i0 * 3 + 2];
    float v1x = vb[i1 * 3 + 0], v1y = vb[i1 * 3 + 1], v1z = vb[i1 * 3 + 2];
    float v2x = vb[i2 * 3 + 0], v2y = vb[i2 * 3 + 1], v2z = vb[i2 * 3 + 2];
    cross3(v1x - v0x, v1y - v0y, v1z - v0z, v2x - v0x, v2y - v0y, v2z - v0z,
           nx, ny, nz);
  }
  {
    const float* vb = tverts + (size_t)b * kV * 3;
    // fp-faithful to reference: add 10 to z BEFORE differencing
    float v0x = vb[i0 * 3 + 0], v0y = vb[i0 * 3 + 1], v0z = vb[i0 * 3 + 2] + 10.0f;
    float v1x = vb[i1 * 3 + 0], v1y = vb[i1 * 3 + 1], v1z = vb[i1 * 3 + 2] + 10.0f;
    float v2x = vb[i2 * 3 + 0], v2y = vb[i2 * 3 + 1], v2z = vb[i2 * 3 + 2] + 10.0f;
    cross3(v1x - v0x, v1y - v0y, v1z - v0z, v2x - v0x, v2y - v0y, v2z - v0z,
           tx, ty, tz);
  }
  fn[(size_t)idx * 2 + 0] = make_float4(nx, ny, nz, tx);
  fn[(size_t)idx * 2 + 1] = make_float4(ty, tz, 0.0f, 0.0f);
}

// Per (b,v): gather-sum adjacent face normals, normalize, write packed
// 16B vertex record {n fp16 x3, tz fp32}.
__global__ void gather_normalize_kernel(const int* __restrict__ cnt,
                                        const int* __restrict__ adj,
                                        const float4* __restrict__ fn,
                                        uint4* __restrict__ vrec) {
  int idx = blockIdx.x * blockDim.x + threadIdx.x;
  if (idx >= kB * kV) return;
  int b = idx / kV;
  int v = idx - b * kV;
  int e = min(cnt[v], kCap);
  float nx = 0.f, ny = 0.f, nz = 0.f, tx = 0.f, ty = 0.f, tzv = 0.f;
  const int* av = adj + v * kCap;
  for (int j = 0; j < e; ++j) {
    int f = av[j];
    size_t k = ((size_t)b * kF + f) * 2;
    float4 a = fn[k];
    float4 c = fn[k + 1];
    nx += a.x;
    ny += a.y;
    nz += a.z;
    tx += a.w;
    ty += c.x;
    tzv += c.y;
  }
  float inv = 1.0f / fmaxf(sqrtf(nx * nx + ny * ny + nz * nz), 1e-6f);
  float invt = 1.0f / fmaxf(sqrtf(tx * tx + ty * ty + tzv * tzv), 1e-6f);
  uint4 r;
  r.x = f2h(nx * inv) | (f2h(ny * inv) << 16);
  r.y = f2h(nz * inv);
  r.z = __float_as_uint(tzv * invt);
  r.w = 0;
  vrec[idx] = r;
}

// Per (b,f): pull 3 packed vertex records (3 x 16B vector gathers) and
// repack into the 32B face record. XCD-affine: b = blockIdx%8 so each XCD's
// L2 only touches one batch's vrec slice.
__global__ void faceattr_kernel(const int* __restrict__ faces,
                                const uint4* __restrict__ vrec,
                                uint4* __restrict__ fattr) {
  // grid = kB * ceil(kF/256) blocks; blockIdx = bchunk*kB + b
  int b = blockIdx.x % kB;
  int f = (blockIdx.x / kB) * blockDim.x + threadIdx.x;
  if (f >= kF) return;
  int idx = b * kF + f;
  int i0 = faces[f * 3 + 0];
  int i1 = faces[f * 3 + 1];
  int i2 = faces[f * 3 + 2];
  const uint4* vb = vrec + (size_t)b * kV;
  uint4 r0 = vb[i0];
  uint4 r1 = vb[i1];
  uint4 r2 = vb[i2];
  uint4 w0, w1;
  w0.x = r0.x;                                      // n0x | n0y
  w0.y = (r0.y & 0xffffu) | (r1.x << 16);           // n0z | n1x
  w0.z = (r1.x >> 16) | ((r1.y & 0xffffu) << 16);   // n1y | n1z
  w0.w = r2.x;                                      // n2x | n2y
  w1.x = r2.y & 0xffffu;                            // n2z
  w1.y = r0.z;                                      // tz0 (f32 bits)
  w1.z = r1.z;                                      // tz1
  w1.w = r2.z;                                      // tz2
  fattr[(size_t)idx * 2 + 0] = w0;
  fattr[(size_t)idx * 2 + 1] = w1;
}

// 4 pixels per thread, round-8 body. XCD-affine batch mapping: b = blockIdx&7
// (8 batches == 8 XCDs) so each XCD's 4MiB L2 holds only ITS batch's 312KB
// fattr slice -> gathers stay L2-resident instead of thrashing to L3.
__global__ void __launch_bounds__(256) pixel4_kernel(
    const int4* __restrict__ p2f4,
    const float4* __restrict__ bary4,
    const uint4* __restrict__ fattr,
    const float4* __restrict__ ldir4,
    const float4* __restrict__ img4,
    float4* __restrict__ out4) {
  // grid = kB * (kQ/256); blockIdx = qchunk*kB + b  ->  dispatch round-robin
  // over XCDs keeps b == XCD id (mod 8).
  int b = blockIdx.x & 7;
  int q = (blockIdx.x >> 3) * blockDim.x + threadIdx.x;
  size_t g = (size_t)b * kQ + q;

  int4 f4 = p2f4[g];
  float4 w0 = bary4[g * 3 + 0];
  float4 w1 = bary4[g * 3 + 1];
  float4 w2 = bary4[g * 3 + 2];

  int fi[4] = {f4.x, f4.y, f4.z, f4.w};
  float bw[4][3] = {{w0.x, w0.y, w0.z},
                    {w0.w, w1.x, w1.y},
                    {w1.z, w1.w, w2.x},
                    {w2.y, w2.z, w2.w}};

  // Issue all 8 gathers (independent -> deep MLP).
  uint4 A[4], T[4];
  bool valid[4];
#pragma unroll
  for (int k = 0; k < 4; ++k) {
    bool v = fi[k] < kF;
    valid[k] = v;
    int f = v ? fi[k] : (kF - 1);
    size_t base = ((size_t)b * kF + f) * 2;
    A[k] = fattr[base + 0];
    T[k] = fattr[base + 1];
  }

  size_t ibase = (size_t)b * 3 * kQ + q;
  float4 im0 = img4[ibase + 0 * (size_t)kQ];
  float4 im1 = img4[ibase + 1 * (size_t)kQ];
  float4 im2 = img4[ibase + 2 * (size_t)kQ];
  float im[3][4] = {{im0.x, im0.y, im0.z, im0.w},
                    {im1.x, im1.y, im1.z, im1.w},
                    {im2.x, im2.y, im2.z, im2.w}};

  // Light data: wave-uniform b -> scalar loads.
  int bu = __builtin_amdgcn_readfirstlane(b);
  const float4* lb4 = ldir4 + (size_t)bu * kL * 2;
  float ld[kL][3], lc[kL][3];
#pragma unroll
  for (int l = 0; l < kL; ++l) {
    float4 d = lb4[l * 2 + 0];
    float4 c = lb4[l * 2 + 1];
    ld[l][0] = d.x;
    ld[l][1] = d.y;
    ld[l][2] = d.z;
    lc[l][0] = c.x;
    lc[l][1] = c.y;
    lc[l][2] = c.z;
  }

  float o[3][4];
#pragma unroll
  for (int k = 0; k < 4; ++k) {
    float b0 = bw[k][0], b1 = bw[k][1], b2 = bw[k][2];
    float inv = 1.0f / (b0 + b1 + b2);
    b0 *= inv;
    b1 *= inv;
    b2 *= inv;
    float n0x = h2f(A[k].x), n0y = h2f(A[k].x >> 16);
    float n0z = h2f(A[k].y), n1x = h2f(A[k].y >> 16);
    float n1y = h2f(A[k].z), n1z = h2f(A[k].z >> 16);
    float n2x = h2f(A[k].w), n2y = h2f(A[k].w >> 16);
    float n2z = h2f(T[k].x);
    float tz0 = __uint_as_float(T[k].y);
    float tz1 = __uint_as_float(T[k].z);
    float tz2 = __uint_as_float(T[k].w);

    float tzi = b0 * tz0 + b1 * tz1 + b2 * tz2;
    bool alpha = valid[k] && (tzi < 0.15f);
    float nx = b0 * n0x + b1 * n1x + b2 * n2x;
    float ny = b0 * n0y + b1 * n1y + b2 * n2y;
    float nz = b0 * n0z + b1 * n1z + b2 * n2z;
    float s0 = 0.f, s1 = 0.f, s2 = 0.f;
#pragma unroll
    for (int l = 0; l < kL; ++l) {
      float d = nx * ld[l][0] + ny * ld[l][1] + nz * ld[l][2];
      d = fminf(fmaxf(d, 0.0f), 1.0f);
      s0 += d * lc[l][0];
      s1 += d * lc[l][1];
      s2 += d * lc[l][2];
    }
    const float kk = (180.0f / 255.0f) / (float)kL;
    o[0][k] = alpha ? kk * s0 : im[0][k];
    o[1][k] = alpha ? kk * s1 : im[1][k];
    o[2][k] = alpha ? kk * s2 : im[2][k];
  }

#pragma unroll
  for (int c = 0; c < 3; ++c) {
    nfloat4 v = {o[c][0], o[c][1], o[c][2], o[c][3]};
    __builtin_nontemporal_store(v, (nfloat4*)&out4[ibase + c * (size_t)kQ]);
  }
}

}  // namespace

extern "C" void kernel_launch(void* const* d_in, const int* in_sizes, int n_in,
                              void* d_out, int out_size, void* d_ws, size_t ws_size,
                              hipStream_t stream) {
  const float* vertices = (const float*)d_in[0];
  const float* tvertices = (const float*)d_in[1];
  const float* lights = (const float*)d_in[2];
  const float* images = (const float*)d_in[3];
  const float* bary = (const float*)d_in[4];
  const int* faces = (const int*)d_in[5];
  const int* p2f = (const int*)d_in[6];
  float* out = (float*)d_out;

  // workspace layout (16B-aligned chunks)
  char* ws = (char*)d_ws;
  int* cnt = (int*)ws;                                   // kV ints
  ws += ((size_t)kV * sizeof(int) + 15) & ~15ull;
  int* adj = (int*)ws;                                   // kV*kCap ints
  ws += ((size_t)kV * kCap * sizeof(int) + 15) & ~15ull;
  float4* fn = (float4*)ws;                              // kB*kF*2 float4
  ws += (size_t)kB * kF * 2 * sizeof(float4);
  uint4* vrec = (uint4*)ws;                              // kB*kV uint4
  ws += (size_t)kB * kV * sizeof(uint4);
  float4* ldir4 = (float4*)ws;                           // kB*kL*2 float4
  ws += (size_t)kB * kL * 2 * sizeof(float4);
  uint4* fattr = (uint4*)ws;                             // kB*kF*2 uint4

  {
    init_kernel<<<20, 256, 0, stream>>>(cnt, lights, ldir4);
  }
  {
    int n = kF + kB * kF;
    prep_kernel<<<(n + 255) / 256, 256, 0, stream>>>(vertices, tvertices, faces, cnt,
                                                     adj, fn);
  }
  {
    int n = kB * kV;
    gather_normalize_kernel<<<(n + 255) / 256, 256, 0, stream>>>(cnt, adj, fn, vrec);
  }
  {
    // XCD-affine: grid = kB * ceil(kF/256), blockIdx = chunk*kB + b
    int chunks = (kF + 255) / 256;
    faceattr_kernel<<<chunks * kB, 256, 0, stream>>>(faces, vrec, fattr);
  }
  {
    // XCD-affine: grid = kB * (kQ/256), blockIdx = qchunk*kB + b
    pixel4_kernel<<<(kQ / 256) * kB, 256, 0, stream>>>(
        (const int4*)p2f, (const float4*)bary, fattr, ldir4, (const float4*)images,
        (float4*)out);
  }
}